// Round 4
// baseline (244.268 us; speedup 1.0000x reference)
//
#include <hip/hip_runtime.h>
#include <math.h>

#define F 128
#define NTOT 2080
#define CN 2048
#define AN 16
#define NA 17   // max agents (step>0)

__device__ __forceinline__ float wmax(float v){
  #pragma unroll
  for(int m=32;m;m>>=1) v = fmaxf(v, __shfl_xor(v, m, 64));
  return v;
}
__device__ __forceinline__ float wsum(float v){
  #pragma unroll
  for(int m=32;m;m>>=1) v += __shfl_xor(v, m, 64);
  return v;
}

// K0a: Wpy = Wp @ Wcy2   (Wpy[k,i] = sum_j Wp[k,j]*Wc[128+j, 128+i])
__global__ __launch_bounds__(128) void k0a_wpy(const float* __restrict__ Wp, const float* __restrict__ Wc,
                                               float* __restrict__ Wpy){
  const int k = blockIdx.x, i = threadIdx.x;
  float acc = 0.f;
  const float* wp = Wp + (size_t)k*F;
  for(int j=0;j<F;j++) acc += wp[j]*Wc[(size_t)(128+j)*256 + 128 + i];
  Wpy[k*F+i] = acc;
}

// K0b: M1 = Wcz2^T @ Wpy  (M1[jc,i] = sum_k Wc[256+k, 128+jc]*Wpy[k,i])
__global__ __launch_bounds__(128) void k0b_m1(const float* __restrict__ Wc, const float* __restrict__ Wpy,
                                              float* __restrict__ M1){
  const int jc = blockIdx.x, i = threadIdx.x;
  float acc = 0.f;
  for(int k=0;k<F;k++) acc += Wc[(size_t)(256+k)*256 + 128 + jc]*Wpy[k*F+i];
  M1[jc*F+i] = acc;
}

// K1: per (b, feature j): segment max/mean over N=2080 (city 2048 | a_start 16 | a_end 16)
__global__ __launch_bounds__(256) void k1_reduce(const float* __restrict__ nf,
                                                 float* __restrict__ glb, float* __restrict__ ave){
  const int j = blockIdx.x, b = blockIdx.y, tid = threadIdx.x;
  const float4* row = (const float4*)(nf + (size_t)(b*F + j)*NTOT);
  float cmax=-INFINITY, csum=0.f, smax=-INFINITY, ssum=0.f, emax=-INFINITY, esum=0.f;
  for(int n4 = tid; n4 < 520; n4 += 256){
    float4 v = row[n4];
    float mx = fmaxf(fmaxf(v.x,v.y), fmaxf(v.z,v.w));
    float sm = (v.x+v.y)+(v.z+v.w);
    if(n4 < 512){ cmax=fmaxf(cmax,mx); csum+=sm; }
    else if(n4 < 516){ smax=fmaxf(smax,mx); ssum+=sm; }
    else { emax=fmaxf(emax,mx); esum+=sm; }
  }
  __shared__ float red[4][6];
  cmax=wmax(cmax); csum=wsum(csum); smax=wmax(smax); ssum=wsum(ssum); emax=wmax(emax); esum=wsum(esum);
  const int lane = tid&63, wid = tid>>6;
  if(lane==0){ red[wid][0]=cmax; red[wid][1]=csum; red[wid][2]=smax; red[wid][3]=ssum; red[wid][4]=emax; red[wid][5]=esum; }
  __syncthreads();
  if(tid==0){
    float cM=red[0][0], cS=red[0][1], sM=red[0][2], sS=red[0][3], eM=red[0][4], eS=red[0][5];
    for(int w=1;w<4;w++){ cM=fmaxf(cM,red[w][0]); cS+=red[w][1]; sM=fmaxf(sM,red[w][2]); sS+=red[w][3]; eM=fmaxf(eM,red[w][4]); eS+=red[w][5]; }
    const int gb = b*4*F;
    glb[gb + j]       = fmaxf(cM, fmaxf(sM,eM));
    glb[gb + F + j]   = cM;
    glb[gb + 2*F + j] = sM;
    glb[gb + 3*F + j] = eM;
    float tS = cS+sS+eS;
    ave[gb + j]       = tS / 2080.f;
    ave[gb + F + j]   = cS / 2048.f;
    ave[gb + 2*F + j] = sS / 16.f;
    ave[gb + 3*F + j] = eS / 16.f;
  }
}

// K2a: per-batch: deglb/fa (wave-split-K, coalesced Wg), cvec, cpy, czc, vz, szc
__global__ __launch_bounds__(256) void k2a_prep(
    const float* __restrict__ Wg, const float* __restrict__ bg,
    const float* __restrict__ Wc, const float* __restrict__ bc,
    const float* __restrict__ Wp, const float* __restrict__ bp,
    const float* __restrict__ Wpy,
    const float* __restrict__ glb, const float* __restrict__ ave,
    float* __restrict__ deglb_g, float* __restrict__ fa_g, float* __restrict__ cx,
    float* __restrict__ czc, float* __restrict__ vz, float* __restrict__ szc){
  const int b = blockIdx.x, tid = threadIdx.x;
  const int lane = tid&63, w = tid>>6;
  __shared__ float glb_s[512], ave_s[512];
  __shared__ float deglb_s[F], cvec_s[3*F], cpy_s[F];
  for(int i=tid;i<512;i+=256){ glb_s[i]=glb[b*512+i]; ave_s[i]=ave[b*512+i]; }
  __syncthreads();
  // deglb (from glb) and fa (from ave): one Wg row load feeds both dots
  for(int jj=0;jj<32;jj++){
    const int j = w*32+jj;
    const float* wr = Wg + (size_t)j*512 + lane*2;
    float a0=0.f, a1=0.f;
    #pragma unroll
    for(int p=0;p<4;p++){
      float2 wv = *(const float2*)(wr + p*128);
      a0 += wv.x*glb_s[p*128+lane*2] + wv.y*glb_s[p*128+lane*2+1];
      a1 += wv.x*ave_s[p*128+lane*2] + wv.y*ave_s[p*128+lane*2+1];
    }
    a0 = wsum(a0); a1 = wsum(a1);
    if(lane==0){
      float d = a0 + bg[j];
      deglb_s[j] = d;
      deglb_g[b*F+j] = d;
      fa_g[b*F+j] = a1 + bg[j];
    }
  }
  __syncthreads();
  // cvec[i] = bc[i] + Wc[i, :128] . deglb   (wave-split-K, coalesced)
  for(int j=w;j<3*F;j+=4){
    float2 wv = *(const float2*)(Wc + (size_t)j*256 + lane*2);
    float acc = wv.x*deglb_s[lane*2] + wv.y*deglb_s[lane*2+1];
    acc = wsum(acc);
    if(lane==0){
      float v = acc + bc[j];
      cvec_s[j] = v;
      if(j<F) cx[b*F+j] = v;
    }
  }
  __syncthreads();
  // cpy[j] = bp[j] + Wp[j,:] . consty (cvec[128:256])
  for(int jj=0;jj<8;jj++){
    const int j = w*32 + jj*4 + (lane>>4);   // spread a bit; still simple
    // simpler: j = w*32+jj with 32 iters; use 32-iter version below instead
  }
  for(int jj=0;jj<32;jj++){
    const int j = w*32+jj;
    float2 wv = *(const float2*)(Wp + (size_t)j*F + lane*2);
    float acc = wv.x*cvec_s[128+lane*2] + wv.y*cvec_s[128+lane*2+1];
    acc = wsum(acc);
    if(lane==0) cpy_s[j] = acc + bp[j];
  }
  __syncthreads();
  // czc[j] = Wcz2^T @ cpy ; vz[j] = Wpy^T @ cz   (coalesced over j, serial k)
  if(tid<128){
    const int j = tid;
    float acc=0.f;
    for(int k=0;k<F;k++) acc += Wc[(size_t)(256+k)*256 + 128 + j]*cpy_s[k];
    czc[b*F+j]=acc;
  } else if(w==2){
    const int j = tid-128;   // lanes of wave 2 -> j 0..63
    float acc0=0.f, acc1=0.f;
    for(int k=0;k<F;k++){
      float c = cvec_s[256+k];
      acc0 += Wpy[k*F+j]*c;
      acc1 += Wpy[k*F+64+j]*c;
    }
    vz[b*F+j]=acc0; vz[b*F+64+j]=acc1;
  } else {
    // wave 3: szc = cpy . cz
    float p = cpy_s[lane]*cvec_s[256+lane] + cpy_s[64+lane]*cvec_s[256+64+lane];
    p = wsum(p);
    if(lane==0) szc[b]=p;
  }
}

// K2c: per (agent a, batch b): af (wave-split-K over Wa), afx (coalesced col pattern), sx
__global__ __launch_bounds__(256) void k2c_agents(
    const float* __restrict__ nf, const float* __restrict__ Wa, const float* __restrict__ ba,
    const float* __restrict__ Wc,
    const float* __restrict__ deglb_g, const float* __restrict__ fa_g, const float* __restrict__ cx,
    float* __restrict__ afx, float* __restrict__ sx){
  const int a = blockIdx.x, b = blockIdx.y, tid = threadIdx.x;
  const int lane = tid&63, w = tid>>6;
  __shared__ float src_s[384];   // [deglb | a_start_a | a_end_a]
  __shared__ float af_s[F], cx_s[F];
  if(tid<128){ src_s[tid] = deglb_g[b*F+tid]; cx_s[tid]=cx[b*F+tid]; }
  else if(a<16){
    const int j = tid-128;
    src_s[128+j] = nf[(size_t)(b*F+j)*NTOT + CN + a];
    src_s[256+j] = nf[(size_t)(b*F+j)*NTOT + CN + AN + a];
  }
  __syncthreads();
  if(a<16){
    for(int jj=0;jj<32;jj++){
      const int j = w*32+jj;
      const float* wr = Wa + (size_t)j*384 + lane*2;
      float acc=0.f;
      #pragma unroll
      for(int p=0;p<3;p++){
        float2 wv = *(const float2*)(wr + p*128);
        acc += wv.x*src_s[p*128+lane*2] + wv.y*src_s[p*128+lane*2+1];
      }
      acc = wsum(acc);
      if(lane==0) af_s[j] = acc + ba[j];
    }
  } else if(tid<128){
    af_s[tid] = fa_g[b*F+tid];
  }
  __syncthreads();
  if(tid<128){ // afx[j] = sum_i af[i]*Wc[i, 128+j]  (coalesced over j)
    const int j = tid;
    float acc=0.f;
    for(int i=0;i<F;i++) acc += af_s[i]*Wc[(size_t)i*256 + 128 + j];
    afx[((size_t)b*NA+a)*F + j]=acc;
  } else if(w==2){ // sx = af . constx
    float p = af_s[lane]*cx_s[lane] + af_s[64+lane]*cx_s[64+lane];
    p = wsum(p);
    if(lane==0) sx[b*NA+a]=p;
  }
}

// K3: ucj[b,a,c] = (afx[a].city[c] + sx[a])*scale ; per-chunk max -> pmax
__global__ __launch_bounds__(256) void k3_scores(const float* __restrict__ nf, const float* __restrict__ afx,
      const float* __restrict__ sx, float* __restrict__ ucj, float* __restrict__ pmax){
  const int b = blockIdx.y, tid = threadIdx.x;
  const int c = blockIdx.x*256 + tid;
  __shared__ float afx_s[NA*F]; __shared__ float sx_s[NA];
  for(int o=tid;o<NA*F;o+=256) afx_s[o]=afx[(size_t)b*NA*F+o];
  if(tid<NA) sx_s[tid]=sx[b*NA+tid];
  __syncthreads();
  float acc[NA];
  #pragma unroll
  for(int a=0;a<NA;a++) acc[a]=0.f;
  const float* base = nf + (size_t)b*F*NTOT + c;
  #pragma unroll 4
  for(int i=0;i<F;i++){
    float v = base[(size_t)i*NTOT];
    #pragma unroll
    for(int a=0;a<NA;a++) acc[a] += afx_s[a*F+i]*v;
  }
  const float scale = 0.088388347648318447f;
  float uc[NA];
  #pragma unroll
  for(int a=0;a<NA;a++){
    uc[a] = (acc[a]+sx_s[a])*scale;
    ucj[((size_t)b*NA + a)*CN + c] = uc[a];
  }
  __shared__ float red[4][NA];
  const int lane = tid&63, wid = tid>>6;
  #pragma unroll
  for(int a=0;a<NA;a++){
    float m = wmax(uc[a]);
    if(lane==0) red[wid][a]=m;
  }
  __syncthreads();
  if(tid<NA){
    float m = fmaxf(fmaxf(red[0][tid],red[1][tid]), fmaxf(red[2][tid],red[3][tid]));
    pmax[(b*NA+tid)*8 + blockIdx.x] = m;
  }
}

// K4: row softmax (in place exp), rowsum
__global__ __launch_bounds__(256) void k4_softmax(float* __restrict__ ucj, const float* __restrict__ pmax,
        float* __restrict__ rowsum){
  const int a = blockIdx.x, b = blockIdx.y, tid = threadIdx.x;
  float m=-INFINITY;
  #pragma unroll
  for(int k=0;k<8;k++) m = fmaxf(m, pmax[(b*NA+a)*8+k]);
  float* row = ucj + ((size_t)b*NA+a)*CN;
  float s=0.f;
  for(int c=tid;c<CN;c+=256){ float e = __expf(row[c]-m); row[c]=e; s+=e; }
  s = wsum(s);
  __shared__ float red[4];
  const int lane=tid&63, wid=tid>>6;
  if(lane==0) red[wid]=s;
  __syncthreads();
  if(tid==0) rowsum[b*NA+a]=red[0]+red[1]+red[2]+red[3];
}

// K5: tpart[chunk][b][a][i] = sum_{c in chunk} attn[a,c]*nf[i,c]
__global__ __launch_bounds__(256) void k5_taccum(const float* __restrict__ nf,
      const float* __restrict__ attn, float* __restrict__ tpart){
  const int b = blockIdx.y, tid = threadIdx.x;
  const int c0 = blockIdx.x*256;
  __shared__ float4 nf4_s[F*16];    // swizzled: [i][g ^ (i&15)]
  __shared__ float4 at4_s[NA*16];   // [a][g] for current 64-city subtile
  const int i = tid&127, h = tid>>7;
  const int A0 = h*8;
  float acc[9];
  #pragma unroll
  for(int a=0;a<9;a++) acc[a]=0.f;
  for(int s4=0;s4<4;s4++){
    const int cs = c0 + s4*64;
    __syncthreads();
    for(int idx=tid; idx<F*16; idx+=256){
      const int ii=idx>>4, g=idx&15;
      nf4_s[ii*16 + (g^(ii&15))] = *(const float4*)(nf + (size_t)(b*F+ii)*NTOT + cs + g*4);
    }
    for(int idx=tid; idx<NA*16; idx+=256){
      const int a=idx>>4, g=idx&15;
      at4_s[idx] = *(const float4*)(attn + ((size_t)b*NA+a)*CN + cs + g*4);
    }
    __syncthreads();
    #pragma unroll 2
    for(int g=0; g<16; g++){
      float4 v = nf4_s[i*16 + (g^(i&15))];
      #pragma unroll
      for(int a=0;a<9;a++){
        float4 w = at4_s[(A0+a)*16+g];
        acc[a] += w.x*v.x + w.y*v.y + w.z*v.z + w.w*v.w;
      }
    }
  }
  float* dst = tpart + (size_t)blockIdx.x*64*NA*F + (size_t)b*NA*F;
  #pragma unroll
  for(int a=0;a<9;a++){
    if(h==0 || a>0) dst[(A0+a)*F + i] = acc[a];
  }
}

// K5b: per (b,a): tn = (sum_k tpart)/rowsum; afz = M1@tn + czc; sz = tn.vz + szc
__global__ __launch_bounds__(128) void k5b_final(const float* __restrict__ M1,
      const float* __restrict__ tpart, const float* __restrict__ rowsum,
      const float* __restrict__ czc, const float* __restrict__ vz, const float* __restrict__ szc,
      float* __restrict__ afz, float* __restrict__ szv){
  const int a = blockIdx.x, b = blockIdx.y, tid = threadIdx.x;
  __shared__ float tn_s[F];
  float s = 0.f;
  #pragma unroll
  for(int k=0;k<8;k++) s += tpart[(size_t)k*64*NA*F + ((size_t)b*NA+a)*F + tid];
  tn_s[tid] = s / rowsum[b*NA+a];
  __syncthreads();
  float acc = 0.f;
  const float* m = M1 + (size_t)tid*F;
  for(int i=0;i<F;i++) acc += m[i]*tn_s[i];
  afz[((size_t)b*NA+a)*F + tid] = acc + czc[b*F+tid];
  float p = tn_s[tid]*vz[b*F+tid];
  p = wsum(p);
  __shared__ float red[2];
  if((tid&63)==0) red[tid>>6]=p;
  __syncthreads();
  if(tid==0) szv[b*NA+a] = red[0]+red[1] + szc[b];
}

// K6: logits = tanh((afz.city + sz)*scale)*10 ; softmax over agents; out[b,c,a]
__global__ __launch_bounds__(256) void k6_out(const float* __restrict__ nf, const float* __restrict__ afz,
      const float* __restrict__ szv, const int* __restrict__ step, float* __restrict__ out){
  const int b = blockIdx.y, tid = threadIdx.x;
  const int c = blockIdx.x*256 + tid;
  __shared__ float afz_s[NA*F]; __shared__ float sz_s[NA];
  for(int o=tid;o<NA*F;o+=256) afz_s[o]=afz[(size_t)b*NA*F+o];
  if(tid<NA) sz_s[tid]=szv[b*NA+tid];
  __syncthreads();
  const int A = (step[0] > 0) ? NA : AN;
  float acc[NA];
  #pragma unroll
  for(int a=0;a<NA;a++) acc[a]=0.f;
  const float* base = nf + (size_t)b*F*NTOT + c;
  #pragma unroll 4
  for(int i=0;i<F;i++){
    float v = base[(size_t)i*NTOT];
    #pragma unroll
    for(int a=0;a<NA;a++) acc[a] += afz_s[a*F+i]*v;
  }
  const float scale = 0.088388347648318447f;
  float l[NA];
  #pragma unroll
  for(int a=0;a<NA;a++) l[a] = tanhf((acc[a]+sz_s[a])*scale)*10.f;
  const bool f17 = (A==NA);
  float m = l[0];
  #pragma unroll
  for(int a=1;a<AN;a++) m = fmaxf(m,l[a]);
  if(f17) m = fmaxf(m,l[16]);
  float ssum=0.f;
  #pragma unroll
  for(int a=0;a<AN;a++){ float e=__expf(l[a]-m); l[a]=e; ssum+=e; }
  float e16=__expf(l[16]-m);
  if(f17){ ssum+=e16; }
  const float inv = 1.f/ssum;
  float* op = out + (size_t)(b*CN + c)*A;
  #pragma unroll
  for(int a=0;a<AN;a++) op[a]=l[a]*inv;
  if(f17) op[16]=e16*inv;
}

extern "C" void kernel_launch(void* const* d_in, const int* in_sizes, int n_in,
                              void* d_out, int out_size, void* d_ws, size_t ws_size,
                              hipStream_t stream){
  const float* nf = (const float*)d_in[0];
  const float* Wg = (const float*)d_in[1];
  const float* bg = (const float*)d_in[2];
  const float* Wc = (const float*)d_in[3];
  const float* bc = (const float*)d_in[4];
  const float* Wa = (const float*)d_in[5];
  const float* ba = (const float*)d_in[6];
  const float* Wp = (const float*)d_in[7];
  const float* bp = (const float*)d_in[8];
  const int*  step = (const int*)d_in[9];
  float* out = (float*)d_out;

  float* ws = (float*)d_ws;
  float* glb     = ws;                    // 64*512
  float* ave     = glb + 64*512;          // 64*512
  float* afx     = ave + 64*512;          // 64*17*128
  float* sx      = afx + 64*NA*F;         // 64*17
  float* Wpy     = sx + 64*NA;            // 128*128
  float* M1      = Wpy + F*F;             // 128*128
  float* czc     = M1 + F*F;              // 64*128
  float* vz      = czc + 64*F;            // 64*128
  float* szc     = vz + 64*F;             // 64
  float* rowsum  = szc + 64;              // 64*17
  float* deglb_g = rowsum + 64*NA;        // 64*128
  float* fa_g    = deglb_g + 64*F;        // 64*128
  float* cx      = fa_g + 64*F;           // 64*128
  float* tpart   = cx + 64*F;             // 8*64*17*128
  float* afz     = tpart + 8*64*NA*F;     // 64*17*128
  float* szv     = afz + 64*NA*F;         // 64*17
  float* ucj     = szv + 64*NA;           // 64*17*2048
  float* pmax    = ucj + (size_t)64*NA*CN;// 64*17*8
  // total ~15.1 MiB of ws

  k0a_wpy<<<F,F,0,stream>>>(Wp, Wc, Wpy);
  k0b_m1<<<F,F,0,stream>>>(Wc, Wpy, M1);
  k1_reduce<<<dim3(128,64),256,0,stream>>>(nf, glb, ave);
  k2a_prep<<<64,256,0,stream>>>(Wg,bg,Wc,bc,Wp,bp, Wpy, glb,ave, deglb_g,fa_g,cx, czc,vz,szc);
  k2c_agents<<<dim3(NA,64),256,0,stream>>>(nf, Wa,ba,Wc, deglb_g,fa_g,cx, afx,sx);
  k3_scores<<<dim3(8,64),256,0,stream>>>(nf, afx, sx, ucj, pmax);
  k4_softmax<<<dim3(NA,64),256,0,stream>>>(ucj, pmax, rowsum);
  k5_taccum<<<dim3(8,64),256,0,stream>>>(nf, ucj, tpart);
  k5b_final<<<dim3(NA,64),128,0,stream>>>(M1, tpart, rowsum, czc, vz, szc, afz, szv);
  k6_out<<<dim3(8,64),256,0,stream>>>(nf, afz, szv, step, out);
}

// Round 5
// 166.722 us; speedup vs baseline: 1.4651x; 1.4651x over previous
//
#include <hip/hip_runtime.h>
#include <math.h>

#define F 128
#define NTOT 2080
#define CN 2048
#define AN 16
#define NA 17   // max agents (step>0)

__device__ __forceinline__ float wmax(float v){
  #pragma unroll
  for(int m=32;m;m>>=1) v = fmaxf(v, __shfl_xor(v, m, 64));
  return v;
}
__device__ __forceinline__ float wsum(float v){
  #pragma unroll
  for(int m=32;m;m>>=1) v += __shfl_xor(v, m, 64);
  return v;
}

// K0t: tiled transposes of Wg(128x512), Wc(384x256), Wp(128x128), Wa(128x384)
__global__ __launch_bounds__(256) void k0t_transpose(
      const float* __restrict__ Wg, const float* __restrict__ Wc,
      const float* __restrict__ Wp, const float* __restrict__ Wa,
      float* __restrict__ WgT, float* __restrict__ WcT,
      float* __restrict__ WpT, float* __restrict__ WaT){
  __shared__ float tile[32][33];
  const int z = blockIdx.z;
  const float* src; float* dst; int R, C;
  if(z==0){ src=Wg; dst=WgT; R=128; C=512; }
  else if(z==1){ src=Wc; dst=WcT; R=384; C=256; }
  else if(z==2){ src=Wp; dst=WpT; R=128; C=128; }
  else { src=Wa; dst=WaT; R=128; C=384; }
  const int c0 = blockIdx.x*32, r0 = blockIdx.y*32;
  if(c0>=C || r0>=R) return;
  const int tx = threadIdx.x&31, ty = threadIdx.x>>5;   // 32x8
  #pragma unroll
  for(int rr=0;rr<4;rr++)
    tile[ty+rr*8][tx] = src[(size_t)(r0+ty+rr*8)*C + c0 + tx];
  __syncthreads();
  #pragma unroll
  for(int rr=0;rr<4;rr++)
    dst[(size_t)(c0+ty+rr*8)*R + r0 + tx] = tile[tx][ty+rr*8];
}

// K0a: Wpy = Wp @ Wcy2   (Wpy[k,i] = sum_j Wp[k,j]*Wc[128+j, 128+i])
__global__ __launch_bounds__(128) void k0a_wpy(const float* __restrict__ Wp, const float* __restrict__ Wc,
                                               float* __restrict__ Wpy){
  const int k = blockIdx.x, i = threadIdx.x;
  float acc = 0.f;
  const float* wp = Wp + (size_t)k*F;
  for(int j=0;j<F;j++) acc += wp[j]*Wc[(size_t)(128+j)*256 + 128 + i];
  Wpy[k*F+i] = acc;
}

// K0b: M1 = Wcz2^T @ Wpy  (M1[jc,i] = sum_k Wc[256+k, 128+jc]*Wpy[k,i])
__global__ __launch_bounds__(128) void k0b_m1(const float* __restrict__ Wc, const float* __restrict__ Wpy,
                                              float* __restrict__ M1){
  const int jc = blockIdx.x, i = threadIdx.x;
  float acc = 0.f;
  for(int k=0;k<F;k++) acc += Wc[(size_t)(256+k)*256 + 128 + jc]*Wpy[k*F+i];
  M1[jc*F+i] = acc;
}

// K1: per (b, feature j): segment max/mean over N=2080 (city 2048 | a_start 16 | a_end 16)
__global__ __launch_bounds__(256) void k1_reduce(const float* __restrict__ nf,
                                                 float* __restrict__ glb, float* __restrict__ ave){
  const int j = blockIdx.x, b = blockIdx.y, tid = threadIdx.x;
  const float4* row = (const float4*)(nf + (size_t)(b*F + j)*NTOT);
  float cmax=-INFINITY, csum=0.f, smax=-INFINITY, ssum=0.f, emax=-INFINITY, esum=0.f;
  for(int n4 = tid; n4 < 520; n4 += 256){
    float4 v = row[n4];
    float mx = fmaxf(fmaxf(v.x,v.y), fmaxf(v.z,v.w));
    float sm = (v.x+v.y)+(v.z+v.w);
    if(n4 < 512){ cmax=fmaxf(cmax,mx); csum+=sm; }
    else if(n4 < 516){ smax=fmaxf(smax,mx); ssum+=sm; }
    else { emax=fmaxf(emax,mx); esum+=sm; }
  }
  __shared__ float red[4][6];
  cmax=wmax(cmax); csum=wsum(csum); smax=wmax(smax); ssum=wsum(ssum); emax=wmax(emax); esum=wsum(esum);
  const int lane = tid&63, wid = tid>>6;
  if(lane==0){ red[wid][0]=cmax; red[wid][1]=csum; red[wid][2]=smax; red[wid][3]=ssum; red[wid][4]=emax; red[wid][5]=esum; }
  __syncthreads();
  if(tid==0){
    float cM=red[0][0], cS=red[0][1], sM=red[0][2], sS=red[0][3], eM=red[0][4], eS=red[0][5];
    for(int w=1;w<4;w++){ cM=fmaxf(cM,red[w][0]); cS+=red[w][1]; sM=fmaxf(sM,red[w][2]); sS+=red[w][3]; eM=fmaxf(eM,red[w][4]); eS+=red[w][5]; }
    const int gb = b*4*F;
    glb[gb + j]       = fmaxf(cM, fmaxf(sM,eM));
    glb[gb + F + j]   = cM;
    glb[gb + 2*F + j] = sM;
    glb[gb + 3*F + j] = eM;
    float tS = cS+sS+eS;
    ave[gb + j]       = tS / 2080.f;
    ave[gb + F + j]   = cS / 2048.f;
    ave[gb + 2*F + j] = sS / 16.f;
    ave[gb + 3*F + j] = eS / 16.f;
  }
}

// K2a: per-batch: deglb/fa (WgT, thread-per-j), cvec (WcT), cpy (WpT) + vz, czc, szc
__global__ __launch_bounds__(256) void k2a_prep(
    const float* __restrict__ WgT, const float* __restrict__ bg,
    const float* __restrict__ WcT, const float* __restrict__ Wc, const float* __restrict__ bc,
    const float* __restrict__ WpT, const float* __restrict__ bp,
    const float* __restrict__ Wpy,
    const float* __restrict__ glb, const float* __restrict__ ave,
    float* __restrict__ deglb_g, float* __restrict__ fa_g, float* __restrict__ cx,
    float* __restrict__ czc, float* __restrict__ vz, float* __restrict__ szc){
  const int b = blockIdx.x, tid = threadIdx.x;
  __shared__ float glb_s[512], ave_s[512];
  __shared__ float deglb_s[F], cvec_s[3*F], cpy_s[F];
  for(int i=tid;i<512;i+=256){ glb_s[i]=glb[b*512+i]; ave_s[i]=ave[b*512+i]; }
  __syncthreads();
  { // deglb (threads 0..127) / fa (threads 128..255): same WgT addresses -> L1 hits
    const int j = tid&127;
    const float* src = (tid<128)? glb_s : ave_s;
    float a0=0.f,a1=0.f,a2=0.f,a3=0.f;
    for(int k=0;k<512;k+=4){
      a0 += WgT[(size_t)(k+0)*128+j]*src[k+0];
      a1 += WgT[(size_t)(k+1)*128+j]*src[k+1];
      a2 += WgT[(size_t)(k+2)*128+j]*src[k+2];
      a3 += WgT[(size_t)(k+3)*128+j]*src[k+3];
    }
    float d = (a0+a1)+(a2+a3) + bg[j];
    if(tid<128){ deglb_s[j]=d; deglb_g[b*F+j]=d; }
    else fa_g[b*F+j]=d;
  }
  __syncthreads();
  // cvec[i] = bc[i] + sum_{k<128} WcT[k*384+i]*deglb[k]
  for(int i=tid;i<3*F;i+=256){
    float a0=0.f,a1=0.f,a2=0.f,a3=0.f;
    for(int k=0;k<F;k+=4){
      a0 += WcT[(size_t)(k+0)*384+i]*deglb_s[k+0];
      a1 += WcT[(size_t)(k+1)*384+i]*deglb_s[k+1];
      a2 += WcT[(size_t)(k+2)*384+i]*deglb_s[k+2];
      a3 += WcT[(size_t)(k+3)*384+i]*deglb_s[k+3];
    }
    float v = (a0+a1)+(a2+a3) + bc[i];
    cvec_s[i]=v;
    if(i<F) cx[b*F+i]=v;
  }
  __syncthreads();
  if(tid<128){ // cpy[j] = bp[j] + Wp[j,:] . consty
    const int j = tid;
    float a0=0.f,a1=0.f,a2=0.f,a3=0.f;
    for(int k=0;k<F;k+=4){
      a0 += WpT[(size_t)(k+0)*128+j]*cvec_s[128+k+0];
      a1 += WpT[(size_t)(k+1)*128+j]*cvec_s[128+k+1];
      a2 += WpT[(size_t)(k+2)*128+j]*cvec_s[128+k+2];
      a3 += WpT[(size_t)(k+3)*128+j]*cvec_s[128+k+3];
    }
    cpy_s[j] = (a0+a1)+(a2+a3) + bp[j];
  } else { // vz[j] = Wpy^T @ cz (independent of cpy)
    const int j = tid-128;
    float a0=0.f,a1=0.f,a2=0.f,a3=0.f;
    for(int k=0;k<F;k+=4){
      a0 += Wpy[(size_t)(k+0)*128+j]*cvec_s[256+k+0];
      a1 += Wpy[(size_t)(k+1)*128+j]*cvec_s[256+k+1];
      a2 += Wpy[(size_t)(k+2)*128+j]*cvec_s[256+k+2];
      a3 += Wpy[(size_t)(k+3)*128+j]*cvec_s[256+k+3];
    }
    vz[b*F+j] = (a0+a1)+(a2+a3);
  }
  __syncthreads();
  if(tid<128){ // czc[j] = Wcz2^T @ cpy (coalesced over j in original Wc)
    const int j = tid;
    float a0=0.f,a1=0.f,a2=0.f,a3=0.f;
    for(int k=0;k<F;k+=4){
      a0 += Wc[(size_t)(256+k+0)*256 + 128 + j]*cpy_s[k+0];
      a1 += Wc[(size_t)(256+k+1)*256 + 128 + j]*cpy_s[k+1];
      a2 += Wc[(size_t)(256+k+2)*256 + 128 + j]*cpy_s[k+2];
      a3 += Wc[(size_t)(256+k+3)*256 + 128 + j]*cpy_s[k+3];
    }
    czc[b*F+j] = (a0+a1)+(a2+a3);
  } else if(tid<192){ // szc = cpy . cz
    const int lane = tid-128;
    float p = cpy_s[lane]*cvec_s[256+lane] + cpy_s[64+lane]*cvec_s[256+64+lane];
    p = wsum(p);
    if(lane==0) szc[b]=p;
  }
}

// K2c: per (agent a, batch b): af (WaT, thread-per-j), afx, sx
__global__ __launch_bounds__(256) void k2c_agents(
    const float* __restrict__ nf, const float* __restrict__ WaT, const float* __restrict__ ba,
    const float* __restrict__ Wc,
    const float* __restrict__ deglb_g, const float* __restrict__ fa_g, const float* __restrict__ cx,
    float* __restrict__ afx, float* __restrict__ sx){
  const int a = blockIdx.x, b = blockIdx.y, tid = threadIdx.x;
  __shared__ float src_s[384];   // [deglb | a_start_a | a_end_a]
  __shared__ float af_s[F], cx_s[F];
  if(tid<128){ src_s[tid] = deglb_g[b*F+tid]; cx_s[tid]=cx[b*F+tid]; }
  else if(a<16){
    const int j = tid-128;
    src_s[128+j] = nf[(size_t)(b*F+j)*NTOT + CN + a];
    src_s[256+j] = nf[(size_t)(b*F+j)*NTOT + CN + AN + a];
  }
  __syncthreads();
  if(a<16){
    if(tid<128){
      const int j = tid;
      float a0=0.f,a1=0.f,a2=0.f,a3=0.f;
      for(int k=0;k<384;k+=4){
        a0 += WaT[(size_t)(k+0)*128+j]*src_s[k+0];
        a1 += WaT[(size_t)(k+1)*128+j]*src_s[k+1];
        a2 += WaT[(size_t)(k+2)*128+j]*src_s[k+2];
        a3 += WaT[(size_t)(k+3)*128+j]*src_s[k+3];
      }
      af_s[j] = (a0+a1)+(a2+a3) + ba[j];
    }
  } else if(tid<128){
    af_s[tid] = fa_g[b*F+tid];
  }
  __syncthreads();
  if(tid<128){ // afx[j] = sum_i af[i]*Wc[i, 128+j]  (coalesced over j)
    const int j = tid;
    float a0=0.f,a1=0.f,a2=0.f,a3=0.f;
    for(int i=0;i<F;i+=4){
      a0 += af_s[i+0]*Wc[(size_t)(i+0)*256 + 128 + j];
      a1 += af_s[i+1]*Wc[(size_t)(i+1)*256 + 128 + j];
      a2 += af_s[i+2]*Wc[(size_t)(i+2)*256 + 128 + j];
      a3 += af_s[i+3]*Wc[(size_t)(i+3)*256 + 128 + j];
    }
    afx[((size_t)b*NA+a)*F + j] = (a0+a1)+(a2+a3);
  } else if(tid<192){ // sx = af . constx
    const int lane = tid-128;
    float p = af_s[lane]*cx_s[lane] + af_s[64+lane]*cx_s[64+lane];
    p = wsum(p);
    if(lane==0) sx[b*NA+a]=p;
  }
}

// K3: ucj[b,a,c] = (afx[a].city[c] + sx[a])*scale ; per-chunk max -> pmax
__global__ __launch_bounds__(256) void k3_scores(const float* __restrict__ nf, const float* __restrict__ afx,
      const float* __restrict__ sx, float* __restrict__ ucj, float* __restrict__ pmax){
  const int b = blockIdx.y, tid = threadIdx.x;
  const int c = blockIdx.x*256 + tid;
  __shared__ float afx_s[NA*F]; __shared__ float sx_s[NA];
  for(int o=tid;o<NA*F;o+=256) afx_s[o]=afx[(size_t)b*NA*F+o];
  if(tid<NA) sx_s[tid]=sx[b*NA+tid];
  __syncthreads();
  float acc[NA];
  #pragma unroll
  for(int a=0;a<NA;a++) acc[a]=0.f;
  const float* base = nf + (size_t)b*F*NTOT + c;
  #pragma unroll 4
  for(int i=0;i<F;i++){
    float v = base[(size_t)i*NTOT];
    #pragma unroll
    for(int a=0;a<NA;a++) acc[a] += afx_s[a*F+i]*v;
  }
  const float scale = 0.088388347648318447f;
  float uc[NA];
  #pragma unroll
  for(int a=0;a<NA;a++){
    uc[a] = (acc[a]+sx_s[a])*scale;
    ucj[((size_t)b*NA + a)*CN + c] = uc[a];
  }
  __shared__ float red[4][NA];
  const int lane = tid&63, wid = tid>>6;
  #pragma unroll
  for(int a=0;a<NA;a++){
    float m = wmax(uc[a]);
    if(lane==0) red[wid][a]=m;
  }
  __syncthreads();
  if(tid<NA){
    float m = fmaxf(fmaxf(red[0][tid],red[1][tid]), fmaxf(red[2][tid],red[3][tid]));
    pmax[(b*NA+tid)*8 + blockIdx.x] = m;
  }
}

// K4: row softmax (in place exp), rowsum
__global__ __launch_bounds__(256) void k4_softmax(float* __restrict__ ucj, const float* __restrict__ pmax,
        float* __restrict__ rowsum){
  const int a = blockIdx.x, b = blockIdx.y, tid = threadIdx.x;
  float m=-INFINITY;
  #pragma unroll
  for(int k=0;k<8;k++) m = fmaxf(m, pmax[(b*NA+a)*8+k]);
  float* row = ucj + ((size_t)b*NA+a)*CN;
  float s=0.f;
  for(int c=tid;c<CN;c+=256){ float e = __expf(row[c]-m); row[c]=e; s+=e; }
  s = wsum(s);
  __shared__ float red[4];
  const int lane=tid&63, wid=tid>>6;
  if(lane==0) red[wid]=s;
  __syncthreads();
  if(tid==0) rowsum[b*NA+a]=red[0]+red[1]+red[2]+red[3];
}

// K5: tpart[chunk][b][a][i] = sum_{c in chunk} attn[a,c]*nf[i,c]
__global__ __launch_bounds__(256) void k5_taccum(const float* __restrict__ nf,
      const float* __restrict__ attn, float* __restrict__ tpart){
  const int b = blockIdx.y, tid = threadIdx.x;
  const int c0 = blockIdx.x*256;
  __shared__ float4 nf4_s[F*16];    // swizzled: [i][g ^ (i&15)]
  __shared__ float4 at4_s[NA*16];   // [a][g] for current 64-city subtile
  const int i = tid&127, h = tid>>7;
  const int A0 = h*8;
  float acc[9];
  #pragma unroll
  for(int a=0;a<9;a++) acc[a]=0.f;
  for(int s4=0;s4<4;s4++){
    const int cs = c0 + s4*64;
    __syncthreads();
    for(int idx=tid; idx<F*16; idx+=256){
      const int ii=idx>>4, g=idx&15;
      nf4_s[ii*16 + (g^(ii&15))] = *(const float4*)(nf + (size_t)(b*F+ii)*NTOT + cs + g*4);
    }
    for(int idx=tid; idx<NA*16; idx+=256){
      const int a=idx>>4, g=idx&15;
      at4_s[idx] = *(const float4*)(attn + ((size_t)b*NA+a)*CN + cs + g*4);
    }
    __syncthreads();
    #pragma unroll 2
    for(int g=0; g<16; g++){
      float4 v = nf4_s[i*16 + (g^(i&15))];
      #pragma unroll
      for(int a=0;a<9;a++){
        float4 w = at4_s[(A0+a)*16+g];
        acc[a] += w.x*v.x + w.y*v.y + w.z*v.z + w.w*v.w;
      }
    }
  }
  float* dst = tpart + (size_t)blockIdx.x*64*NA*F + (size_t)b*NA*F;
  #pragma unroll
  for(int a=0;a<9;a++){
    if(h==0 || a>0) dst[(A0+a)*F + i] = acc[a];
  }
}

// K5b: per (b,a): tn = (sum_k tpart)/rowsum; afz = M1@tn + czc; sz = tn.vz + szc
__global__ __launch_bounds__(128) void k5b_final(const float* __restrict__ M1,
      const float* __restrict__ tpart, const float* __restrict__ rowsum,
      const float* __restrict__ czc, const float* __restrict__ vz, const float* __restrict__ szc,
      float* __restrict__ afz, float* __restrict__ szv){
  const int a = blockIdx.x, b = blockIdx.y, tid = threadIdx.x;
  __shared__ float tn_s[F];
  float s = 0.f;
  #pragma unroll
  for(int k=0;k<8;k++) s += tpart[(size_t)k*64*NA*F + ((size_t)b*NA+a)*F + tid];
  tn_s[tid] = s / rowsum[b*NA+a];
  __syncthreads();
  float acc = 0.f;
  const float* m = M1 + (size_t)tid*F;
  for(int i=0;i<F;i++) acc += m[i]*tn_s[i];
  afz[((size_t)b*NA+a)*F + tid] = acc + czc[b*F+tid];
  float p = tn_s[tid]*vz[b*F+tid];
  p = wsum(p);
  __shared__ float red[2];
  if((tid&63)==0) red[tid>>6]=p;
  __syncthreads();
  if(tid==0) szv[b*NA+a] = red[0]+red[1] + szc[b];
}

// K6: logits = tanh((afz.city + sz)*scale)*10 ; softmax over agents; out[b,c,a]
__global__ __launch_bounds__(256) void k6_out(const float* __restrict__ nf, const float* __restrict__ afz,
      const float* __restrict__ szv, const int* __restrict__ step, float* __restrict__ out){
  const int b = blockIdx.y, tid = threadIdx.x;
  const int c = blockIdx.x*256 + tid;
  __shared__ float afz_s[NA*F]; __shared__ float sz_s[NA];
  for(int o=tid;o<NA*F;o+=256) afz_s[o]=afz[(size_t)b*NA*F+o];
  if(tid<NA) sz_s[tid]=szv[b*NA+tid];
  __syncthreads();
  const int A = (step[0] > 0) ? NA : AN;
  float acc[NA];
  #pragma unroll
  for(int a=0;a<NA;a++) acc[a]=0.f;
  const float* base = nf + (size_t)b*F*NTOT + c;
  #pragma unroll 4
  for(int i=0;i<F;i++){
    float v = base[(size_t)i*NTOT];
    #pragma unroll
    for(int a=0;a<NA;a++) acc[a] += afz_s[a*F+i]*v;
  }
  const float scale = 0.088388347648318447f;
  float l[NA];
  #pragma unroll
  for(int a=0;a<NA;a++) l[a] = tanhf((acc[a]+sz_s[a])*scale)*10.f;
  const bool f17 = (A==NA);
  float m = l[0];
  #pragma unroll
  for(int a=1;a<AN;a++) m = fmaxf(m,l[a]);
  if(f17) m = fmaxf(m,l[16]);
  float ssum=0.f;
  #pragma unroll
  for(int a=0;a<AN;a++){ float e=__expf(l[a]-m); l[a]=e; ssum+=e; }
  float e16=__expf(l[16]-m);
  if(f17){ ssum+=e16; }
  const float inv = 1.f/ssum;
  float* op = out + (size_t)(b*CN + c)*A;
  #pragma unroll
  for(int a=0;a<AN;a++) op[a]=l[a]*inv;
  if(f17) op[16]=e16*inv;
}

extern "C" void kernel_launch(void* const* d_in, const int* in_sizes, int n_in,
                              void* d_out, int out_size, void* d_ws, size_t ws_size,
                              hipStream_t stream){
  const float* nf = (const float*)d_in[0];
  const float* Wg = (const float*)d_in[1];
  const float* bg = (const float*)d_in[2];
  const float* Wc = (const float*)d_in[3];
  const float* bc = (const float*)d_in[4];
  const float* Wa = (const float*)d_in[5];
  const float* ba = (const float*)d_in[6];
  const float* Wp = (const float*)d_in[7];
  const float* bp = (const float*)d_in[8];
  const int*  step = (const int*)d_in[9];
  float* out = (float*)d_out;

  float* ws = (float*)d_ws;
  float* glb     = ws;                    // 64*512
  float* ave     = glb + 64*512;          // 64*512
  float* afx     = ave + 64*512;          // 64*17*128
  float* sx      = afx + 64*NA*F;         // 64*17
  float* Wpy     = sx + 64*NA;            // 128*128
  float* M1      = Wpy + F*F;             // 128*128
  float* czc     = M1 + F*F;              // 64*128
  float* vz      = czc + 64*F;            // 64*128
  float* szc     = vz + 64*F;             // 64
  float* rowsum  = szc + 64;              // 64*17
  float* deglb_g = rowsum + 64*NA;        // 64*128
  float* fa_g    = deglb_g + 64*F;        // 64*128
  float* cx      = fa_g + 64*F;           // 64*128
  float* WgT     = cx + 64*F;             // 512*128
  float* WcT     = WgT + 512*F;           // 256*384
  float* WpT     = WcT + 256*384;         // 128*128
  float* WaT     = WpT + F*F;             // 384*128
  float* tpart   = WaT + 384*F;           // 8*64*17*128
  float* afz     = tpart + 8*64*NA*F;     // 64*17*128
  float* szv     = afz + 64*NA*F;         // 64*17
  float* ucj     = szv + 64*NA;           // 64*17*2048
  float* pmax    = ucj + (size_t)64*NA*CN;// 64*17*8
  // total ~16 MiB of ws

  k0t_transpose<<<dim3(16,12,4),256,0,stream>>>(Wg,Wc,Wp,Wa, WgT,WcT,WpT,WaT);
  k0a_wpy<<<F,F,0,stream>>>(Wp, Wc, Wpy);
  k0b_m1<<<F,F,0,stream>>>(Wc, Wpy, M1);
  k1_reduce<<<dim3(128,64),256,0,stream>>>(nf, glb, ave);
  k2a_prep<<<64,256,0,stream>>>(WgT,bg, WcT,Wc,bc, WpT,bp, Wpy, glb,ave, deglb_g,fa_g,cx, czc,vz,szc);
  k2c_agents<<<dim3(NA,64),256,0,stream>>>(nf, WaT,ba,Wc, deglb_g,fa_g,cx, afx,sx);
  k3_scores<<<dim3(8,64),256,0,stream>>>(nf, afx, sx, ucj, pmax);
  k4_softmax<<<dim3(NA,64),256,0,stream>>>(ucj, pmax, rowsum);
  k5_taccum<<<dim3(8,64),256,0,stream>>>(nf, ucj, tpart);
  k5b_final<<<dim3(NA,64),128,0,stream>>>(M1, tpart, rowsum, czc, vz, szc, afz, szv);
  k6_out<<<dim3(8,64),256,0,stream>>>(nf, afz, szv, step, out);
}

// Round 6
// 157.959 us; speedup vs baseline: 1.5464x; 1.0555x over previous
//
#include <hip/hip_runtime.h>
#include <math.h>

#define F 128
#define NTOT 2080
#define CN 2048
#define AN 16
#define NA 17   // max agents (step>0)

__device__ __forceinline__ float wmax(float v){
  #pragma unroll
  for(int m=32;m;m>>=1) v = fmaxf(v, __shfl_xor(v, m, 64));
  return v;
}
__device__ __forceinline__ float wsum(float v){
  #pragma unroll
  for(int m=32;m;m>>=1) v += __shfl_xor(v, m, 64);
  return v;
}

// K0t: tiled transposes of Wg(128x512), Wc(384x256), Wp(128x128), Wa(128x384)
__global__ __launch_bounds__(256) void k0t_transpose(
      const float* __restrict__ Wg, const float* __restrict__ Wc,
      const float* __restrict__ Wp, const float* __restrict__ Wa,
      float* __restrict__ WgT, float* __restrict__ WcT,
      float* __restrict__ WpT, float* __restrict__ WaT){
  __shared__ float tile[32][33];
  const int z = blockIdx.z;
  const float* src; float* dst; int R, C;
  if(z==0){ src=Wg; dst=WgT; R=128; C=512; }
  else if(z==1){ src=Wc; dst=WcT; R=384; C=256; }
  else if(z==2){ src=Wp; dst=WpT; R=128; C=128; }
  else { src=Wa; dst=WaT; R=128; C=384; }
  const int c0 = blockIdx.x*32, r0 = blockIdx.y*32;
  if(c0>=C || r0>=R) return;
  const int tx = threadIdx.x&31, ty = threadIdx.x>>5;   // 32x8
  #pragma unroll
  for(int rr=0;rr<4;rr++)
    tile[ty+rr*8][tx] = src[(size_t)(r0+ty+rr*8)*C + c0 + tx];
  __syncthreads();
  #pragma unroll
  for(int rr=0;rr<4;rr++)
    dst[(size_t)(c0+ty+rr*8)*R + r0 + tx] = tile[tx][ty+rr*8];
}

// K0a: Wpy = Wp @ Wcy2   (Wpy[k,i] = sum_j Wp[k,j]*Wc[128+j, 128+i])
__global__ __launch_bounds__(128) void k0a_wpy(const float* __restrict__ Wp, const float* __restrict__ Wc,
                                               float* __restrict__ Wpy){
  const int k = blockIdx.x, i = threadIdx.x;
  float acc = 0.f;
  const float* wp = Wp + (size_t)k*F;
  for(int j=0;j<F;j++) acc += wp[j]*Wc[(size_t)(128+j)*256 + 128 + i];
  Wpy[k*F+i] = acc;
}

// K0b: M1 = Wcz2^T @ Wpy  (M1[jc,i] = sum_k Wc[256+k, 128+jc]*Wpy[k,i])
__global__ __launch_bounds__(128) void k0b_m1(const float* __restrict__ Wc, const float* __restrict__ Wpy,
                                              float* __restrict__ M1){
  const int jc = blockIdx.x, i = threadIdx.x;
  float acc = 0.f;
  for(int k=0;k<F;k++) acc += Wc[(size_t)(256+k)*256 + 128 + jc]*Wpy[k*F+i];
  M1[jc*F+i] = acc;
}

// K1: per (b, feature j): segment max/mean over N=2080 (city 2048 | a_start 16 | a_end 16)
__global__ __launch_bounds__(256) void k1_reduce(const float* __restrict__ nf,
                                                 float* __restrict__ glb, float* __restrict__ ave){
  const int j = blockIdx.x, b = blockIdx.y, tid = threadIdx.x;
  const float4* row = (const float4*)(nf + (size_t)(b*F + j)*NTOT);
  float cmax=-INFINITY, csum=0.f, smax=-INFINITY, ssum=0.f, emax=-INFINITY, esum=0.f;
  for(int n4 = tid; n4 < 520; n4 += 256){
    float4 v = row[n4];
    float mx = fmaxf(fmaxf(v.x,v.y), fmaxf(v.z,v.w));
    float sm = (v.x+v.y)+(v.z+v.w);
    if(n4 < 512){ cmax=fmaxf(cmax,mx); csum+=sm; }
    else if(n4 < 516){ smax=fmaxf(smax,mx); ssum+=sm; }
    else { emax=fmaxf(emax,mx); esum+=sm; }
  }
  __shared__ float red[4][6];
  cmax=wmax(cmax); csum=wsum(csum); smax=wmax(smax); ssum=wsum(ssum); emax=wmax(emax); esum=wsum(esum);
  const int lane = tid&63, wid = tid>>6;
  if(lane==0){ red[wid][0]=cmax; red[wid][1]=csum; red[wid][2]=smax; red[wid][3]=ssum; red[wid][4]=emax; red[wid][5]=esum; }
  __syncthreads();
  if(tid==0){
    float cM=red[0][0], cS=red[0][1], sM=red[0][2], sS=red[0][3], eM=red[0][4], eS=red[0][5];
    for(int w=1;w<4;w++){ cM=fmaxf(cM,red[w][0]); cS+=red[w][1]; sM=fmaxf(sM,red[w][2]); sS+=red[w][3]; eM=fmaxf(eM,red[w][4]); eS+=red[w][5]; }
    const int gb = b*4*F;
    glb[gb + j]       = fmaxf(cM, fmaxf(sM,eM));
    glb[gb + F + j]   = cM;
    glb[gb + 2*F + j] = sM;
    glb[gb + 3*F + j] = eM;
    float tS = cS+sS+eS;
    ave[gb + j]       = tS / 2080.f;
    ave[gb + F + j]   = cS / 2048.f;
    ave[gb + 2*F + j] = sS / 16.f;
    ave[gb + 3*F + j] = eS / 16.f;
  }
}

// K2a: per-batch: deglb/fa (WgT, thread-per-j), cvec (WcT), cpy (WpT) + vz, czc, szc
__global__ __launch_bounds__(256) void k2a_prep(
    const float* __restrict__ WgT, const float* __restrict__ bg,
    const float* __restrict__ WcT, const float* __restrict__ Wc, const float* __restrict__ bc,
    const float* __restrict__ WpT, const float* __restrict__ bp,
    const float* __restrict__ Wpy,
    const float* __restrict__ glb, const float* __restrict__ ave,
    float* __restrict__ deglb_g, float* __restrict__ fa_g, float* __restrict__ cx,
    float* __restrict__ czc, float* __restrict__ vz, float* __restrict__ szc){
  const int b = blockIdx.x, tid = threadIdx.x;
  __shared__ float glb_s[512], ave_s[512];
  __shared__ float deglb_s[F], cvec_s[3*F], cpy_s[F];
  for(int i=tid;i<512;i+=256){ glb_s[i]=glb[b*512+i]; ave_s[i]=ave[b*512+i]; }
  __syncthreads();
  { // deglb (threads 0..127) / fa (threads 128..255): same WgT addresses -> L1 hits
    const int j = tid&127;
    const float* src = (tid<128)? glb_s : ave_s;
    float a0=0.f,a1=0.f,a2=0.f,a3=0.f;
    for(int k=0;k<512;k+=4){
      a0 += WgT[(size_t)(k+0)*128+j]*src[k+0];
      a1 += WgT[(size_t)(k+1)*128+j]*src[k+1];
      a2 += WgT[(size_t)(k+2)*128+j]*src[k+2];
      a3 += WgT[(size_t)(k+3)*128+j]*src[k+3];
    }
    float d = (a0+a1)+(a2+a3) + bg[j];
    if(tid<128){ deglb_s[j]=d; deglb_g[b*F+j]=d; }
    else fa_g[b*F+j]=d;
  }
  __syncthreads();
  // cvec[i] = bc[i] + sum_{k<128} WcT[k*384+i]*deglb[k]
  for(int i=tid;i<3*F;i+=256){
    float a0=0.f,a1=0.f,a2=0.f,a3=0.f;
    for(int k=0;k<F;k+=4){
      a0 += WcT[(size_t)(k+0)*384+i]*deglb_s[k+0];
      a1 += WcT[(size_t)(k+1)*384+i]*deglb_s[k+1];
      a2 += WcT[(size_t)(k+2)*384+i]*deglb_s[k+2];
      a3 += WcT[(size_t)(k+3)*384+i]*deglb_s[k+3];
    }
    float v = (a0+a1)+(a2+a3) + bc[i];
    cvec_s[i]=v;
    if(i<F) cx[b*F+i]=v;
  }
  __syncthreads();
  if(tid<128){ // cpy[j] = bp[j] + Wp[j,:] . consty
    const int j = tid;
    float a0=0.f,a1=0.f,a2=0.f,a3=0.f;
    for(int k=0;k<F;k+=4){
      a0 += WpT[(size_t)(k+0)*128+j]*cvec_s[128+k+0];
      a1 += WpT[(size_t)(k+1)*128+j]*cvec_s[128+k+1];
      a2 += WpT[(size_t)(k+2)*128+j]*cvec_s[128+k+2];
      a3 += WpT[(size_t)(k+3)*128+j]*cvec_s[128+k+3];
    }
    cpy_s[j] = (a0+a1)+(a2+a3) + bp[j];
  } else { // vz[j] = Wpy^T @ cz (independent of cpy)
    const int j = tid-128;
    float a0=0.f,a1=0.f,a2=0.f,a3=0.f;
    for(int k=0;k<F;k+=4){
      a0 += Wpy[(size_t)(k+0)*128+j]*cvec_s[256+k+0];
      a1 += Wpy[(size_t)(k+1)*128+j]*cvec_s[256+k+1];
      a2 += Wpy[(size_t)(k+2)*128+j]*cvec_s[256+k+2];
      a3 += Wpy[(size_t)(k+3)*128+j]*cvec_s[256+k+3];
    }
    vz[b*F+j] = (a0+a1)+(a2+a3);
  }
  __syncthreads();
  if(tid<128){ // czc[j] = Wcz2^T @ cpy (coalesced over j in original Wc)
    const int j = tid;
    float a0=0.f,a1=0.f,a2=0.f,a3=0.f;
    for(int k=0;k<F;k+=4){
      a0 += Wc[(size_t)(256+k+0)*256 + 128 + j]*cpy_s[k+0];
      a1 += Wc[(size_t)(256+k+1)*256 + 128 + j]*cpy_s[k+1];
      a2 += Wc[(size_t)(256+k+2)*256 + 128 + j]*cpy_s[k+2];
      a3 += Wc[(size_t)(256+k+3)*256 + 128 + j]*cpy_s[k+3];
    }
    czc[b*F+j] = (a0+a1)+(a2+a3);
  } else if(tid<192){ // szc = cpy . cz
    const int lane = tid-128;
    float p = cpy_s[lane]*cvec_s[256+lane] + cpy_s[64+lane]*cvec_s[256+64+lane];
    p = wsum(p);
    if(lane==0) szc[b]=p;
  }
}

// K2c: per (agent a, batch b): af (WaT, thread-per-j), afx, sx
__global__ __launch_bounds__(256) void k2c_agents(
    const float* __restrict__ nf, const float* __restrict__ WaT, const float* __restrict__ ba,
    const float* __restrict__ Wc,
    const float* __restrict__ deglb_g, const float* __restrict__ fa_g, const float* __restrict__ cx,
    float* __restrict__ afx, float* __restrict__ sx){
  const int a = blockIdx.x, b = blockIdx.y, tid = threadIdx.x;
  __shared__ float src_s[384];   // [deglb | a_start_a | a_end_a]
  __shared__ float af_s[F], cx_s[F];
  if(tid<128){ src_s[tid] = deglb_g[b*F+tid]; cx_s[tid]=cx[b*F+tid]; }
  else if(a<16){
    const int j = tid-128;
    src_s[128+j] = nf[(size_t)(b*F+j)*NTOT + CN + a];
    src_s[256+j] = nf[(size_t)(b*F+j)*NTOT + CN + AN + a];
  }
  __syncthreads();
  if(a<16){
    if(tid<128){
      const int j = tid;
      float a0=0.f,a1=0.f,a2=0.f,a3=0.f;
      for(int k=0;k<384;k+=4){
        a0 += WaT[(size_t)(k+0)*128+j]*src_s[k+0];
        a1 += WaT[(size_t)(k+1)*128+j]*src_s[k+1];
        a2 += WaT[(size_t)(k+2)*128+j]*src_s[k+2];
        a3 += WaT[(size_t)(k+3)*128+j]*src_s[k+3];
      }
      af_s[j] = (a0+a1)+(a2+a3) + ba[j];
    }
  } else if(tid<128){
    af_s[tid] = fa_g[b*F+tid];
  }
  __syncthreads();
  if(tid<128){ // afx[j] = sum_i af[i]*Wc[i, 128+j]  (coalesced over j)
    const int j = tid;
    float a0=0.f,a1=0.f,a2=0.f,a3=0.f;
    for(int i=0;i<F;i+=4){
      a0 += af_s[i+0]*Wc[(size_t)(i+0)*256 + 128 + j];
      a1 += af_s[i+1]*Wc[(size_t)(i+1)*256 + 128 + j];
      a2 += af_s[i+2]*Wc[(size_t)(i+2)*256 + 128 + j];
      a3 += af_s[i+3]*Wc[(size_t)(i+3)*256 + 128 + j];
    }
    afx[((size_t)b*NA+a)*F + j] = (a0+a1)+(a2+a3);
  } else if(tid<192){ // sx = af . constx
    const int lane = tid-128;
    float p = af_s[lane]*cx_s[lane] + af_s[64+lane]*cx_s[64+lane];
    p = wsum(p);
    if(lane==0) sx[b*NA+a]=p;
  }
}

// K35: fused scores + chunk-local softmax + t-accum (flash style).
// Per (chunk of 256 cities, b): uc[a] per city -> chunk max m_k -> e=exp(uc-m_k)
// (kept in LDS) -> s_k = sum e -> tpart_k[a][i] = sum_c e*nf[i][c] (unnormalized).
__global__ __launch_bounds__(256) void k35_flash(const float* __restrict__ nf,
      const float* __restrict__ afx, const float* __restrict__ sx,
      float* __restrict__ pmax, float* __restrict__ psum, float* __restrict__ tpart){
  const int b = blockIdx.y, tid = threadIdx.x;
  const int chunk = blockIdx.x, c0 = chunk*256;
  __shared__ float afx_s[NA*F];
  __shared__ float sx_s[NA];
  __shared__ float at_s[NA*256];    // exp scores, [a][c] — 16B-aligned rows
  __shared__ float4 nf4_s[F*16];    // swizzled 64-city subtile
  __shared__ float red_s[4][NA];
  __shared__ float m_s[NA];
  for(int o=tid;o<NA*F;o+=256) afx_s[o]=afx[(size_t)b*NA*F+o];
  if(tid<NA) sx_s[tid]=sx[b*NA+tid];
  __syncthreads();
  // phase 1: scores for city c = c0+tid
  float acc[NA];
  #pragma unroll
  for(int a=0;a<NA;a++) acc[a]=0.f;
  {
    const float* base = nf + (size_t)b*F*NTOT + c0 + tid;
    #pragma unroll 4
    for(int i=0;i<F;i++){
      float v = base[(size_t)i*NTOT];
      #pragma unroll
      for(int a=0;a<NA;a++) acc[a] += afx_s[a*F+i]*v;
    }
  }
  const float scale = 0.088388347648318447f;
  #pragma unroll
  for(int a=0;a<NA;a++) acc[a] = (acc[a]+sx_s[a])*scale;
  // phase 2: per-agent chunk max
  const int lane = tid&63, wid = tid>>6;
  #pragma unroll
  for(int a=0;a<NA;a++){
    float m = wmax(acc[a]);
    if(lane==0) red_s[wid][a]=m;
  }
  __syncthreads();
  if(tid<NA){
    float m = fmaxf(fmaxf(red_s[0][tid],red_s[1][tid]), fmaxf(red_s[2][tid],red_s[3][tid]));
    m_s[tid]=m;
    pmax[(b*NA+tid)*8 + chunk]=m;
  }
  __syncthreads();
  // phase 3: e = exp(uc-m); store to LDS; chunk expsum
  #pragma unroll
  for(int a=0;a<NA;a++){
    float e = __expf(acc[a]-m_s[a]);
    at_s[a*256+tid]=e;
    float s = wsum(e);
    if(lane==0) red_s[wid][a]=s;
  }
  __syncthreads();
  if(tid<NA)
    psum[(b*NA+tid)*8 + chunk] = red_s[0][tid]+red_s[1][tid]+red_s[2][tid]+red_s[3][tid];
  // phase 4: tpart accumulation (k5 pattern, scores from at_s as b128 broadcast)
  const int i = tid&127, h = tid>>7, A0 = h*8;
  float ta[9];
  #pragma unroll
  for(int a=0;a<9;a++) ta[a]=0.f;
  for(int s4=0;s4<4;s4++){
    const int cs = c0 + s4*64;
    __syncthreads();   // protect nf4_s (and at_s on first iter)
    for(int idx=tid; idx<F*16; idx+=256){
      const int ii=idx>>4, g=idx&15;
      nf4_s[ii*16 + (g^(ii&15))] = *(const float4*)(nf + (size_t)(b*F+ii)*NTOT + cs + g*4);
    }
    __syncthreads();
    #pragma unroll 2
    for(int g=0; g<16; g++){
      float4 v = nf4_s[i*16 + (g^(i&15))];
      #pragma unroll
      for(int a=0;a<9;a++){
        float4 w = *(const float4*)&at_s[(A0+a)*256 + s4*64 + g*4];
        ta[a] += w.x*v.x + w.y*v.y + w.z*v.z + w.w*v.w;
      }
    }
  }
  float* dst = tpart + (size_t)chunk*64*NA*F + (size_t)b*NA*F;
  #pragma unroll
  for(int a=0;a<9;a++){
    if(h==0 || a>0) dst[(A0+a)*F + i] = ta[a];
  }
}

// K5c: per (b,a): combine chunks with rescale; tn; afz = M1@tn + czc; sz = tn.vz + szc
__global__ __launch_bounds__(128) void k5c_final(const float* __restrict__ M1,
      const float* __restrict__ tpart, const float* __restrict__ pmax, const float* __restrict__ psum,
      const float* __restrict__ czc, const float* __restrict__ vz, const float* __restrict__ szc,
      float* __restrict__ afz, float* __restrict__ szv){
  const int a = blockIdx.x, b = blockIdx.y, tid = threadIdx.x;
  __shared__ float tn_s[F];
  const float* pm = pmax + (b*NA+a)*8;
  const float* ps = psum + (b*NA+a)*8;
  float M=-INFINITY;
  #pragma unroll
  for(int k=0;k<8;k++) M = fmaxf(M, pm[k]);
  float w[8]; float rs=0.f;
  #pragma unroll
  for(int k=0;k<8;k++){ w[k]=__expf(pm[k]-M); rs += ps[k]*w[k]; }
  float s = 0.f;
  #pragma unroll
  for(int k=0;k<8;k++) s += tpart[(size_t)k*64*NA*F + ((size_t)b*NA+a)*F + tid]*w[k];
  tn_s[tid] = s / rs;
  __syncthreads();
  float acc = 0.f;
  const float* m = M1 + (size_t)tid*F;
  for(int i=0;i<F;i++) acc += m[i]*tn_s[i];
  afz[((size_t)b*NA+a)*F + tid] = acc + czc[b*F+tid];
  float p = tn_s[tid]*vz[b*F+tid];
  p = wsum(p);
  __shared__ float red[2];
  if((tid&63)==0) red[tid>>6]=p;
  __syncthreads();
  if(tid==0) szv[b*NA+a] = red[0]+red[1] + szc[b];
}

// K6: logits = tanh((afz.city + sz)*scale)*10 ; softmax over agents; out[b,c,a]
__global__ __launch_bounds__(256) void k6_out(const float* __restrict__ nf, const float* __restrict__ afz,
      const float* __restrict__ szv, const int* __restrict__ step, float* __restrict__ out){
  const int b = blockIdx.y, tid = threadIdx.x;
  const int c = blockIdx.x*256 + tid;
  __shared__ float afz_s[NA*F]; __shared__ float sz_s[NA];
  for(int o=tid;o<NA*F;o+=256) afz_s[o]=afz[(size_t)b*NA*F+o];
  if(tid<NA) sz_s[tid]=szv[b*NA+tid];
  __syncthreads();
  const int A = (step[0] > 0) ? NA : AN;
  float acc[NA];
  #pragma unroll
  for(int a=0;a<NA;a++) acc[a]=0.f;
  const float* base = nf + (size_t)b*F*NTOT + c;
  #pragma unroll 4
  for(int i=0;i<F;i++){
    float v = base[(size_t)i*NTOT];
    #pragma unroll
    for(int a=0;a<NA;a++) acc[a] += afz_s[a*F+i]*v;
  }
  const float scale = 0.088388347648318447f;
  float l[NA];
  #pragma unroll
  for(int a=0;a<NA;a++) l[a] = tanhf((acc[a]+sz_s[a])*scale)*10.f;
  const bool f17 = (A==NA);
  float m = l[0];
  #pragma unroll
  for(int a=1;a<AN;a++) m = fmaxf(m,l[a]);
  if(f17) m = fmaxf(m,l[16]);
  float ssum=0.f;
  #pragma unroll
  for(int a=0;a<AN;a++){ float e=__expf(l[a]-m); l[a]=e; ssum+=e; }
  float e16=__expf(l[16]-m);
  if(f17){ ssum+=e16; }
  const float inv = 1.f/ssum;
  float* op = out + (size_t)(b*CN + c)*A;
  #pragma unroll
  for(int a=0;a<AN;a++) op[a]=l[a]*inv;
  if(f17) op[16]=e16*inv;
}

extern "C" void kernel_launch(void* const* d_in, const int* in_sizes, int n_in,
                              void* d_out, int out_size, void* d_ws, size_t ws_size,
                              hipStream_t stream){
  const float* nf = (const float*)d_in[0];
  const float* Wg = (const float*)d_in[1];
  const float* bg = (const float*)d_in[2];
  const float* Wc = (const float*)d_in[3];
  const float* bc = (const float*)d_in[4];
  const float* Wa = (const float*)d_in[5];
  const float* ba = (const float*)d_in[6];
  const float* Wp = (const float*)d_in[7];
  const float* bp = (const float*)d_in[8];
  const int*  step = (const int*)d_in[9];
  float* out = (float*)d_out;

  float* ws = (float*)d_ws;
  float* glb     = ws;                    // 64*512
  float* ave     = glb + 64*512;          // 64*512
  float* afx     = ave + 64*512;          // 64*17*128
  float* sx      = afx + 64*NA*F;         // 64*17
  float* Wpy     = sx + 64*NA;            // 128*128
  float* M1      = Wpy + F*F;             // 128*128
  float* czc     = M1 + F*F;              // 64*128
  float* vz      = czc + 64*F;            // 64*128
  float* szc     = vz + 64*F;             // 64
  float* pmax    = szc + 64;              // 64*17*8
  float* psum    = pmax + 64*NA*8;        // 64*17*8
  float* deglb_g = psum + 64*NA*8;        // 64*128
  float* fa_g    = deglb_g + 64*F;        // 64*128
  float* cx      = fa_g + 64*F;           // 64*128
  float* WgT     = cx + 64*F;             // 512*128
  float* WcT     = WgT + 512*F;           // 256*384
  float* WpT     = WcT + 256*384;         // 128*128
  float* WaT     = WpT + F*F;             // 384*128
  float* tpart   = WaT + 384*F;           // 8*64*17*128
  float* afz     = tpart + 8*64*NA*F;     // 64*17*128
  float* szv     = afz + 64*NA*F;         // 64*17
  // total ~7.5 MiB of ws

  k0t_transpose<<<dim3(16,12,4),256,0,stream>>>(Wg,Wc,Wp,Wa, WgT,WcT,WpT,WaT);
  k0a_wpy<<<F,F,0,stream>>>(Wp, Wc, Wpy);
  k0b_m1<<<F,F,0,stream>>>(Wc, Wpy, M1);
  k1_reduce<<<dim3(128,64),256,0,stream>>>(nf, glb, ave);
  k2a_prep<<<64,256,0,stream>>>(WgT,bg, WcT,Wc,bc, WpT,bp, Wpy, glb,ave, deglb_g,fa_g,cx, czc,vz,szc);
  k2c_agents<<<dim3(NA,64),256,0,stream>>>(nf, WaT,ba,Wc, deglb_g,fa_g,cx, afx,sx);
  k35_flash<<<dim3(8,64),256,0,stream>>>(nf, afx, sx, pmax, psum, tpart);
  k5c_final<<<dim3(NA,64),128,0,stream>>>(M1, tpart, pmax, psum, czc, vz, szc, afz, szv);
  k6_out<<<dim3(8,64),256,0,stream>>>(nf, afz, szv, step, out);
}

// Round 7
// 153.007 us; speedup vs baseline: 1.5964x; 1.0324x over previous
//
#include <hip/hip_runtime.h>
#include <math.h>

#define F 128
#define NTOT 2080
#define CN 2048
#define AN 16
#define NA 17   // max agents (step>0)
#define CHK 128 // cities per chunk (k35/k6)
#define NCHK 16 // CN/CHK

__device__ __forceinline__ float wmax(float v){
  #pragma unroll
  for(int m=32;m;m>>=1) v = fmaxf(v, __shfl_xor(v, m, 64));
  return v;
}
__device__ __forceinline__ float wsum(float v){
  #pragma unroll
  for(int m=32;m;m>>=1) v += __shfl_xor(v, m, 64);
  return v;
}

// K0t: tiled transposes of Wg(128x512), Wc(384x256), Wp(128x128), Wa(128x384)
__global__ __launch_bounds__(256) void k0t_transpose(
      const float* __restrict__ Wg, const float* __restrict__ Wc,
      const float* __restrict__ Wp, const float* __restrict__ Wa,
      float* __restrict__ WgT, float* __restrict__ WcT,
      float* __restrict__ WpT, float* __restrict__ WaT){
  __shared__ float tile[32][33];
  const int z = blockIdx.z;
  const float* src; float* dst; int R, C;
  if(z==0){ src=Wg; dst=WgT; R=128; C=512; }
  else if(z==1){ src=Wc; dst=WcT; R=384; C=256; }
  else if(z==2){ src=Wp; dst=WpT; R=128; C=128; }
  else { src=Wa; dst=WaT; R=128; C=384; }
  const int c0 = blockIdx.x*32, r0 = blockIdx.y*32;
  if(c0>=C || r0>=R) return;
  const int tx = threadIdx.x&31, ty = threadIdx.x>>5;   // 32x8
  #pragma unroll
  for(int rr=0;rr<4;rr++)
    tile[ty+rr*8][tx] = src[(size_t)(r0+ty+rr*8)*C + c0 + tx];
  __syncthreads();
  #pragma unroll
  for(int rr=0;rr<4;rr++)
    dst[(size_t)(c0+ty+rr*8)*R + r0 + tx] = tile[tx][ty+rr*8];
}

// K0a: Wpy = Wp @ Wcy2   (Wpy[k,i] = sum_j Wp[k,j]*Wc[128+j, 128+i])
__global__ __launch_bounds__(128) void k0a_wpy(const float* __restrict__ Wp, const float* __restrict__ Wc,
                                               float* __restrict__ Wpy){
  const int k = blockIdx.x, i = threadIdx.x;
  float acc = 0.f;
  const float* wp = Wp + (size_t)k*F;
  for(int j=0;j<F;j++) acc += wp[j]*Wc[(size_t)(128+j)*256 + 128 + i];
  Wpy[k*F+i] = acc;
}

// K0b: M1 = Wcz2^T @ Wpy  (M1[jc,i] = sum_k Wc[256+k, 128+jc]*Wpy[k,i])
__global__ __launch_bounds__(128) void k0b_m1(const float* __restrict__ Wc, const float* __restrict__ Wpy,
                                              float* __restrict__ M1){
  const int jc = blockIdx.x, i = threadIdx.x;
  float acc = 0.f;
  for(int k=0;k<F;k++) acc += Wc[(size_t)(256+k)*256 + 128 + jc]*Wpy[k*F+i];
  M1[jc*F+i] = acc;
}

// K1: per (b, j-group of 4): one wave per feature row, segment max/mean over N=2080
__global__ __launch_bounds__(256) void k1_reduce(const float* __restrict__ nf,
                                                 float* __restrict__ glb, float* __restrict__ ave){
  const int jg = blockIdx.x, b = blockIdx.y;
  const int w = threadIdx.x>>6, lane = threadIdx.x&63;
  const int j = jg*4 + w;
  const float4* row = (const float4*)(nf + (size_t)(b*F + j)*NTOT);
  float cmax=-INFINITY, csum=0.f, smax=-INFINITY, ssum=0.f, emax=-INFINITY, esum=0.f;
  for(int n4 = lane; n4 < 520; n4 += 64){
    float4 v = row[n4];
    float mx = fmaxf(fmaxf(v.x,v.y), fmaxf(v.z,v.w));
    float sm = (v.x+v.y)+(v.z+v.w);
    if(n4 < 512){ cmax=fmaxf(cmax,mx); csum+=sm; }
    else if(n4 < 516){ smax=fmaxf(smax,mx); ssum+=sm; }
    else { emax=fmaxf(emax,mx); esum+=sm; }
  }
  cmax=wmax(cmax); csum=wsum(csum); smax=wmax(smax); ssum=wsum(ssum); emax=wmax(emax); esum=wsum(esum);
  if(lane==0){
    const int gb = b*4*F;
    glb[gb + j]       = fmaxf(cmax, fmaxf(smax,emax));
    glb[gb + F + j]   = cmax;
    glb[gb + 2*F + j] = smax;
    glb[gb + 3*F + j] = emax;
    float tS = csum+ssum+esum;
    ave[gb + j]       = tS / 2080.f;
    ave[gb + F + j]   = csum / 2048.f;
    ave[gb + 2*F + j] = ssum / 16.f;
    ave[gb + 3*F + j] = esum / 16.f;
  }
}

// K2a: per-batch: deglb/fa (WgT, thread-per-j), cvec (WcT), cpy (WpT) + vz, czc, szc
__global__ __launch_bounds__(256) void k2a_prep(
    const float* __restrict__ WgT, const float* __restrict__ bg,
    const float* __restrict__ WcT, const float* __restrict__ Wc, const float* __restrict__ bc,
    const float* __restrict__ WpT, const float* __restrict__ bp,
    const float* __restrict__ Wpy,
    const float* __restrict__ glb, const float* __restrict__ ave,
    float* __restrict__ deglb_g, float* __restrict__ fa_g, float* __restrict__ cx,
    float* __restrict__ czc, float* __restrict__ vz, float* __restrict__ szc){
  const int b = blockIdx.x, tid = threadIdx.x;
  __shared__ float glb_s[512], ave_s[512];
  __shared__ float deglb_s[F], cvec_s[3*F], cpy_s[F];
  for(int i=tid;i<512;i+=256){ glb_s[i]=glb[b*512+i]; ave_s[i]=ave[b*512+i]; }
  __syncthreads();
  { // deglb (threads 0..127) / fa (threads 128..255): same WgT addresses -> L1 hits
    const int j = tid&127;
    const float* src = (tid<128)? glb_s : ave_s;
    float a0=0.f,a1=0.f,a2=0.f,a3=0.f;
    for(int k=0;k<512;k+=4){
      a0 += WgT[(size_t)(k+0)*128+j]*src[k+0];
      a1 += WgT[(size_t)(k+1)*128+j]*src[k+1];
      a2 += WgT[(size_t)(k+2)*128+j]*src[k+2];
      a3 += WgT[(size_t)(k+3)*128+j]*src[k+3];
    }
    float d = (a0+a1)+(a2+a3) + bg[j];
    if(tid<128){ deglb_s[j]=d; deglb_g[b*F+j]=d; }
    else fa_g[b*F+j]=d;
  }
  __syncthreads();
  // cvec[i] = bc[i] + sum_{k<128} WcT[k*384+i]*deglb[k]
  for(int i=tid;i<3*F;i+=256){
    float a0=0.f,a1=0.f,a2=0.f,a3=0.f;
    for(int k=0;k<F;k+=4){
      a0 += WcT[(size_t)(k+0)*384+i]*deglb_s[k+0];
      a1 += WcT[(size_t)(k+1)*384+i]*deglb_s[k+1];
      a2 += WcT[(size_t)(k+2)*384+i]*deglb_s[k+2];
      a3 += WcT[(size_t)(k+3)*384+i]*deglb_s[k+3];
    }
    float v = (a0+a1)+(a2+a3) + bc[i];
    cvec_s[i]=v;
    if(i<F) cx[b*F+i]=v;
  }
  __syncthreads();
  if(tid<128){ // cpy[j] = bp[j] + Wp[j,:] . consty
    const int j = tid;
    float a0=0.f,a1=0.f,a2=0.f,a3=0.f;
    for(int k=0;k<F;k+=4){
      a0 += WpT[(size_t)(k+0)*128+j]*cvec_s[128+k+0];
      a1 += WpT[(size_t)(k+1)*128+j]*cvec_s[128+k+1];
      a2 += WpT[(size_t)(k+2)*128+j]*cvec_s[128+k+2];
      a3 += WpT[(size_t)(k+3)*128+j]*cvec_s[128+k+3];
    }
    cpy_s[j] = (a0+a1)+(a2+a3) + bp[j];
  } else { // vz[j] = Wpy^T @ cz (independent of cpy)
    const int j = tid-128;
    float a0=0.f,a1=0.f,a2=0.f,a3=0.f;
    for(int k=0;k<F;k+=4){
      a0 += Wpy[(size_t)(k+0)*128+j]*cvec_s[256+k+0];
      a1 += Wpy[(size_t)(k+1)*128+j]*cvec_s[256+k+1];
      a2 += Wpy[(size_t)(k+2)*128+j]*cvec_s[256+k+2];
      a3 += Wpy[(size_t)(k+3)*128+j]*cvec_s[256+k+3];
    }
    vz[b*F+j] = (a0+a1)+(a2+a3);
  }
  __syncthreads();
  if(tid<128){ // czc[j] = Wcz2^T @ cpy (coalesced over j in original Wc)
    const int j = tid;
    float a0=0.f,a1=0.f,a2=0.f,a3=0.f;
    for(int k=0;k<F;k+=4){
      a0 += Wc[(size_t)(256+k+0)*256 + 128 + j]*cpy_s[k+0];
      a1 += Wc[(size_t)(256+k+1)*256 + 128 + j]*cpy_s[k+1];
      a2 += Wc[(size_t)(256+k+2)*256 + 128 + j]*cpy_s[k+2];
      a3 += Wc[(size_t)(256+k+3)*256 + 128 + j]*cpy_s[k+3];
    }
    czc[b*F+j] = (a0+a1)+(a2+a3);
  } else if(tid<192){ // szc = cpy . cz
    const int lane = tid-128;
    float p = cpy_s[lane]*cvec_s[256+lane] + cpy_s[64+lane]*cvec_s[256+64+lane];
    p = wsum(p);
    if(lane==0) szc[b]=p;
  }
}

// K2c: per (agent a, batch b): af (WaT, thread-per-j), afx, sx
__global__ __launch_bounds__(256) void k2c_agents(
    const float* __restrict__ nf, const float* __restrict__ WaT, const float* __restrict__ ba,
    const float* __restrict__ Wc,
    const float* __restrict__ deglb_g, const float* __restrict__ fa_g, const float* __restrict__ cx,
    float* __restrict__ afx, float* __restrict__ sx){
  const int a = blockIdx.x, b = blockIdx.y, tid = threadIdx.x;
  __shared__ float src_s[384];   // [deglb | a_start_a | a_end_a]
  __shared__ float af_s[F], cx_s[F];
  if(tid<128){ src_s[tid] = deglb_g[b*F+tid]; cx_s[tid]=cx[b*F+tid]; }
  else if(a<16){
    const int j = tid-128;
    src_s[128+j] = nf[(size_t)(b*F+j)*NTOT + CN + a];
    src_s[256+j] = nf[(size_t)(b*F+j)*NTOT + CN + AN + a];
  }
  __syncthreads();
  if(a<16){
    if(tid<128){
      const int j = tid;
      float a0=0.f,a1=0.f,a2=0.f,a3=0.f;
      for(int k=0;k<384;k+=4){
        a0 += WaT[(size_t)(k+0)*128+j]*src_s[k+0];
        a1 += WaT[(size_t)(k+1)*128+j]*src_s[k+1];
        a2 += WaT[(size_t)(k+2)*128+j]*src_s[k+2];
        a3 += WaT[(size_t)(k+3)*128+j]*src_s[k+3];
      }
      af_s[j] = (a0+a1)+(a2+a3) + ba[j];
    }
  } else if(tid<128){
    af_s[tid] = fa_g[b*F+tid];
  }
  __syncthreads();
  if(tid<128){ // afx[j] = sum_i af[i]*Wc[i, 128+j]  (coalesced over j)
    const int j = tid;
    float a0=0.f,a1=0.f,a2=0.f,a3=0.f;
    for(int i=0;i<F;i+=4){
      a0 += af_s[i+0]*Wc[(size_t)(i+0)*256 + 128 + j];
      a1 += af_s[i+1]*Wc[(size_t)(i+1)*256 + 128 + j];
      a2 += af_s[i+2]*Wc[(size_t)(i+2)*256 + 128 + j];
      a3 += af_s[i+3]*Wc[(size_t)(i+3)*256 + 128 + j];
    }
    afx[((size_t)b*NA+a)*F + j] = (a0+a1)+(a2+a3);
  } else if(tid<192){ // sx = af . constx
    const int lane = tid-128;
    float p = af_s[lane]*cx_s[lane] + af_s[64+lane]*cx_s[64+lane];
    p = wsum(p);
    if(lane==0) sx[b*NA+a]=p;
  }
}

// K35: fused scores + chunk softmax + t-accum. Chunk=128 cities, split-K halves.
__global__ __launch_bounds__(256) void k35_flash(const float* __restrict__ nf,
      const float* __restrict__ afx, const float* __restrict__ sx,
      float* __restrict__ pmax, float* __restrict__ psum, float* __restrict__ tpart){
  const int b = blockIdx.y, tid = threadIdx.x;
  const int chunk = blockIdx.x, c0 = chunk*CHK;
  __shared__ float afx_s[NA*F];
  __shared__ float sx_s[NA];
  __shared__ float at_s[NA*CHK];   // partial scores, then exp scores
  __shared__ float4 nf4_s[F*8];    // swizzled 32-city subtile
  __shared__ float red_s[2][NA];
  __shared__ float m_s[NA];
  for(int o=tid;o<NA*F;o+=256) afx_s[o]=afx[(size_t)b*NA*F+o];
  if(tid<NA) sx_s[tid]=sx[b*NA+tid];
  __syncthreads();
  const int h = tid>>7, cl = tid&127, i0 = h*64;
  // phase 1: half-K score partials for city c0+cl (float4 afx broadcast reads)
  float acc[NA];
  #pragma unroll
  for(int a=0;a<NA;a++) acc[a]=0.f;
  {
    const float* base = nf + (size_t)b*F*NTOT + (size_t)i0*NTOT + c0 + cl;
    for(int q=0;q<16;q++){
      float v0 = base[(size_t)(q*4+0)*NTOT];
      float v1 = base[(size_t)(q*4+1)*NTOT];
      float v2 = base[(size_t)(q*4+2)*NTOT];
      float v3 = base[(size_t)(q*4+3)*NTOT];
      #pragma unroll
      for(int a=0;a<NA;a++){
        float4 w = *(const float4*)&afx_s[a*F + i0 + q*4];
        acc[a] += w.x*v0 + w.y*v1 + w.z*v2 + w.w*v3;
      }
    }
  }
  if(h==0){
    #pragma unroll
    for(int a=0;a<NA;a++) at_s[a*CHK+cl] = acc[a];
  }
  __syncthreads();
  const int lane = tid&63;
  const float scale = 0.088388347648318447f;
  if(h==1){
    const int wq = (tid>>6)&1;
    #pragma unroll
    for(int a=0;a<NA;a++){
      acc[a] = (acc[a] + at_s[a*CHK+cl] + sx_s[a])*scale;
      float m = wmax(acc[a]);
      if(lane==0) red_s[wq][a]=m;
    }
  }
  __syncthreads();
  if(tid<NA){
    float m = fmaxf(red_s[0][tid], red_s[1][tid]);
    m_s[tid]=m;
    pmax[(b*NA+tid)*NCHK + chunk]=m;
  }
  __syncthreads();
  if(h==1){
    const int wq = (tid>>6)&1;
    #pragma unroll
    for(int a=0;a<NA;a++){
      float e = __expf(acc[a]-m_s[a]);
      at_s[a*CHK+cl]=e;
      float s = wsum(e);
      if(lane==0) red_s[wq][a]=s;
    }
  }
  __syncthreads();
  if(tid<NA)
    psum[(b*NA+tid)*NCHK + chunk] = red_s[0][tid]+red_s[1][tid];
  // phase 4: tpart over 4 subtiles of 32 cities
  const int i = tid&127, A0 = h*8;
  float ta[9];
  #pragma unroll
  for(int a=0;a<9;a++) ta[a]=0.f;
  for(int s4=0;s4<4;s4++){
    const int csl = s4*32, cs = c0 + csl;
    __syncthreads();   // protect nf4_s (and at_s completion on first iter)
    for(int idx=tid; idx<F*8; idx+=256){
      const int ii=idx>>3, g=idx&7;
      nf4_s[ii*8 + (g^(ii&7))] = *(const float4*)(nf + (size_t)(b*F+ii)*NTOT + cs + g*4);
    }
    __syncthreads();
    #pragma unroll 2
    for(int g=0; g<8; g++){
      float4 v = nf4_s[i*8 + (g^(i&7))];
      #pragma unroll
      for(int a=0;a<9;a++){
        float4 w = *(const float4*)&at_s[(A0+a)*CHK + csl + g*4];
        ta[a] += w.x*v.x + w.y*v.y + w.z*v.z + w.w*v.w;
      }
    }
  }
  float* dst = tpart + (size_t)chunk*64*NA*F + (size_t)b*NA*F;
  #pragma unroll
  for(int a=0;a<9;a++){
    if(h==0 || a>0) dst[(A0+a)*F + i] = ta[a];
  }
}

// K5c: per (b,a): combine 16 chunks with rescale; tn; afz = M1@tn + czc; sz = tn.vz + szc
__global__ __launch_bounds__(128) void k5c_final(const float* __restrict__ M1,
      const float* __restrict__ tpart, const float* __restrict__ pmax, const float* __restrict__ psum,
      const float* __restrict__ czc, const float* __restrict__ vz, const float* __restrict__ szc,
      float* __restrict__ afz, float* __restrict__ szv){
  const int a = blockIdx.x, b = blockIdx.y, tid = threadIdx.x;
  __shared__ float tn_s[F];
  const float* pm = pmax + (b*NA+a)*NCHK;
  const float* ps = psum + (b*NA+a)*NCHK;
  float M=-INFINITY;
  #pragma unroll
  for(int k=0;k<NCHK;k++) M = fmaxf(M, pm[k]);
  float w[NCHK]; float rs=0.f;
  #pragma unroll
  for(int k=0;k<NCHK;k++){ w[k]=__expf(pm[k]-M); rs += ps[k]*w[k]; }
  float s = 0.f;
  #pragma unroll
  for(int k=0;k<NCHK;k++) s += tpart[(size_t)k*64*NA*F + ((size_t)b*NA+a)*F + tid]*w[k];
  tn_s[tid] = s / rs;
  __syncthreads();
  float acc = 0.f;
  const float* m = M1 + (size_t)tid*F;
  for(int i=0;i<F;i++) acc += m[i]*tn_s[i];
  afz[((size_t)b*NA+a)*F + tid] = acc + czc[b*F+tid];
  float p = tn_s[tid]*vz[b*F+tid];
  p = wsum(p);
  __shared__ float red[2];
  if((tid&63)==0) red[tid>>6]=p;
  __syncthreads();
  if(tid==0) szv[b*NA+a] = red[0]+red[1] + szc[b];
}

// K6: logits + tanh + agent softmax. Chunk=128 cities, split-K halves, float4 afz reads.
__global__ __launch_bounds__(256) void k6_out(const float* __restrict__ nf, const float* __restrict__ afz,
      const float* __restrict__ szv, const int* __restrict__ step, float* __restrict__ out){
  const int b = blockIdx.y, tid = threadIdx.x;
  const int chunk = blockIdx.x, c0 = chunk*CHK;
  __shared__ float afz_s[NA*F]; __shared__ float sz_s[NA];
  __shared__ float sc_s[NA*CHK];
  for(int o=tid;o<NA*F;o+=256) afz_s[o]=afz[(size_t)b*NA*F+o];
  if(tid<NA) sz_s[tid]=szv[b*NA+tid];
  __syncthreads();
  const int h = tid>>7, cl = tid&127, i0 = h*64;
  float acc[NA];
  #pragma unroll
  for(int a=0;a<NA;a++) acc[a]=0.f;
  {
    const float* base = nf + (size_t)b*F*NTOT + (size_t)i0*NTOT + c0 + cl;
    for(int q=0;q<16;q++){
      float v0 = base[(size_t)(q*4+0)*NTOT];
      float v1 = base[(size_t)(q*4+1)*NTOT];
      float v2 = base[(size_t)(q*4+2)*NTOT];
      float v3 = base[(size_t)(q*4+3)*NTOT];
      #pragma unroll
      for(int a=0;a<NA;a++){
        float4 w = *(const float4*)&afz_s[a*F + i0 + q*4];
        acc[a] += w.x*v0 + w.y*v1 + w.z*v2 + w.w*v3;
      }
    }
  }
  if(h==0){
    #pragma unroll
    for(int a=0;a<NA;a++) sc_s[a*CHK+cl] = acc[a];
  }
  __syncthreads();
  if(h==1){
    const int A = (step[0] > 0) ? NA : AN;
    const float scale = 0.088388347648318447f;
    float l[NA];
    #pragma unroll
    for(int a=0;a<NA;a++)
      l[a] = tanhf((acc[a] + sc_s[a*CHK+cl] + sz_s[a])*scale)*10.f;
    const bool f17 = (A==NA);
    float m = l[0];
    #pragma unroll
    for(int a=1;a<AN;a++) m = fmaxf(m,l[a]);
    if(f17) m = fmaxf(m,l[16]);
    float ssum=0.f;
    #pragma unroll
    for(int a=0;a<AN;a++){ float e=__expf(l[a]-m); l[a]=e; ssum+=e; }
    float e16=__expf(l[16]-m);
    if(f17){ ssum+=e16; }
    const float inv = 1.f/ssum;
    float* op = out + (size_t)(b*CN + c0 + cl)*A;
    #pragma unroll
    for(int a=0;a<AN;a++) op[a]=l[a]*inv;
    if(f17) op[16]=e16*inv;
  }
}

extern "C" void kernel_launch(void* const* d_in, const int* in_sizes, int n_in,
                              void* d_out, int out_size, void* d_ws, size_t ws_size,
                              hipStream_t stream){
  const float* nf = (const float*)d_in[0];
  const float* Wg = (const float*)d_in[1];
  const float* bg = (const float*)d_in[2];
  const float* Wc = (const float*)d_in[3];
  const float* bc = (const float*)d_in[4];
  const float* Wa = (const float*)d_in[5];
  const float* ba = (const float*)d_in[6];
  const float* Wp = (const float*)d_in[7];
  const float* bp = (const float*)d_in[8];
  const int*  step = (const int*)d_in[9];
  float* out = (float*)d_out;

  float* ws = (float*)d_ws;
  float* glb     = ws;                    // 64*512
  float* ave     = glb + 64*512;          // 64*512
  float* afx     = ave + 64*512;          // 64*17*128
  float* sx      = afx + 64*NA*F;         // 64*17
  float* Wpy     = sx + 64*NA;            // 128*128
  float* M1      = Wpy + F*F;             // 128*128
  float* czc     = M1 + F*F;              // 64*128
  float* vz      = czc + 64*F;            // 64*128
  float* szc     = vz + 64*F;             // 64
  float* pmax    = szc + 64;              // 64*17*16
  float* psum    = pmax + 64*NA*NCHK;     // 64*17*16
  float* deglb_g = psum + 64*NA*NCHK;     // 64*128
  float* fa_g    = deglb_g + 64*F;        // 64*128
  float* cx      = fa_g + 64*F;           // 64*128
  float* WgT     = cx + 64*F;             // 512*128
  float* WcT     = WgT + 512*F;           // 256*384
  float* WpT     = WcT + 256*384;         // 128*128
  float* WaT     = WpT + F*F;             // 384*128
  float* tpart   = WaT + 384*F;           // 16*64*17*128
  float* afz     = tpart + (size_t)NCHK*64*NA*F;  // 64*17*128
  float* szv     = afz + 64*NA*F;         // 64*17
  // total ~12 MiB of ws

  k0t_transpose<<<dim3(16,12,4),256,0,stream>>>(Wg,Wc,Wp,Wa, WgT,WcT,WpT,WaT);
  k0a_wpy<<<F,F,0,stream>>>(Wp, Wc, Wpy);
  k0b_m1<<<F,F,0,stream>>>(Wc, Wpy, M1);
  k1_reduce<<<dim3(32,64),256,0,stream>>>(nf, glb, ave);
  k2a_prep<<<64,256,0,stream>>>(WgT,bg, WcT,Wc,bc, WpT,bp, Wpy, glb,ave, deglb_g,fa_g,cx, czc,vz,szc);
  k2c_agents<<<dim3(NA,64),256,0,stream>>>(nf, WaT,ba,Wc, deglb_g,fa_g,cx, afx,sx);
  k35_flash<<<dim3(NCHK,64),256,0,stream>>>(nf, afx, sx, pmax, psum, tpart);
  k5c_final<<<dim3(NA,64),128,0,stream>>>(M1, tpart, pmax, psum, czc, vz, szc, afz, szv);
  k6_out<<<dim3(NCHK,64),256,0,stream>>>(nf, afz, szv, step, out);
}